// Round 1
// baseline (225.131 us; speedup 1.0000x reference)
//
#include <hip/hip_runtime.h>
#include <hip/hip_bf16.h>

#define C_NUM 100000
#define D_EMB 512
#define N_BATCH 512
#define SCALE_F 30.0f
#define MARGIN_F 0.4f
#define H_F 0.333f

typedef __attribute__((ext_vector_type(8))) short bf16x8;
typedef __attribute__((ext_vector_type(4))) short bf16x4;
typedef __attribute__((ext_vector_type(4))) float f32x4;

static __device__ __forceinline__ short f2bf(float f) {
  __hip_bfloat16 h = __float2bfloat16(f);
  union { __hip_bfloat16 b; short s; } u;
  u.b = h;
  return u.s;
}

// ---------------------------------------------------------------------------
// Kernel 1: per-row L2 norm of embeddings; write unit-normalized rows as bf16.
// One wave per row.
// ---------------------------------------------------------------------------
__global__ __launch_bounds__(64) void k_rownorm(const float* __restrict__ emb,
                                                short* __restrict__ Aunit,
                                                float* __restrict__ norms) {
  const int i = blockIdx.x;     // row
  const int l = threadIdx.x;    // lane 0..63
  const f32x4* row = reinterpret_cast<const f32x4*>(emb + (size_t)i * D_EMB);
  f32x4 v0 = row[l];
  f32x4 v1 = row[l + 64];
  float ss = v0[0]*v0[0] + v0[1]*v0[1] + v0[2]*v0[2] + v0[3]*v0[3]
           + v1[0]*v1[0] + v1[1]*v1[1] + v1[2]*v1[2] + v1[3]*v1[3];
#pragma unroll
  for (int m = 1; m < 64; m <<= 1) ss += __shfl_xor(ss, m);
  float nrm = sqrtf(ss);
  float inv = 1.0f / nrm;
  bf16x4 o0, o1;
#pragma unroll
  for (int q = 0; q < 4; ++q) { o0[q] = f2bf(v0[q] * inv); o1[q] = f2bf(v1[q] * inv); }
  bf16x4* dst = reinterpret_cast<bf16x4*>(Aunit + (size_t)i * D_EMB);
  dst[l] = o0;
  dst[l + 64] = o1;
  if (l == 0) norms[i] = nrm;
}

// ---------------------------------------------------------------------------
// Kernel 2: batch mean / unbiased std of norms -> adaptive margin per row.
// Also zeroes the sumexp accumulator for this launch.
// ---------------------------------------------------------------------------
__global__ __launch_bounds__(512) void k_stats(const float* __restrict__ norms,
                                               float* __restrict__ marg,
                                               float* __restrict__ sumexp) {
  __shared__ float red[8];
  const int t = threadIdx.x;          // 0..511
  const int lane = t & 63, wid = t >> 6;
  float x = norms[t];
  float s = x;
#pragma unroll
  for (int m = 1; m < 64; m <<= 1) s += __shfl_xor(s, m);
  if (lane == 0) red[wid] = s;
  __syncthreads();
  float tot = 0.f;
#pragma unroll
  for (int q = 0; q < 8; ++q) tot += red[q];
  const float mean = tot / 512.f;
  __syncthreads();
  float d = x - mean;
  float s2 = d * d;
#pragma unroll
  for (int m = 1; m < 64; m <<= 1) s2 += __shfl_xor(s2, m);
  if (lane == 0) red[wid] = s2;
  __syncthreads();
  float tot2 = 0.f;
#pragma unroll
  for (int q = 0; q < 8; ++q) tot2 += red[q];
  const float stdv = sqrtf(tot2 / 511.f);   // ddof=1
  float msc = (x - mean) / (stdv + H_F);
  msc = fminf(1.f, fmaxf(-1.f, msc));
  marg[t] = MARGIN_F * (1.f + msc);
  sumexp[t] = 0.f;
}

// ---------------------------------------------------------------------------
// Kernel 3: main. Each block handles a 64-class tile x all 512 rows.
// - stage weight tile (64 x 512) as bf16 into LDS (XOR-swizzled), fusing
//   per-class sum-of-squares -> 1/||w_c||
// - 8 waves, each owns 64 rows x 64 cols via 4x4 fragments of 16x16x32 bf16
// - epilogue: margin at label hits, sum of exp(30*cos) per row, one
//   atomicAdd per row per block.
// ---------------------------------------------------------------------------
__global__ __launch_bounds__(512) void k_main(const short* __restrict__ Aunit,
                                              const float* __restrict__ weight,
                                              const int* __restrict__ labels,
                                              const float* __restrict__ marg,
                                              float* __restrict__ sumexp,
                                              float* __restrict__ tlogit) {
  __shared__ alignas(16) short Bs[64 * 512];   // 64 KiB bf16 weight tile
  __shared__ float winv[64];
  __shared__ int lab[512];
  __shared__ float rowsum[512];

  const int tid = threadIdx.x;
  const int c0 = blockIdx.x * 64;
  char* BsB = reinterpret_cast<char*>(Bs);

  lab[tid] = labels[tid];

  // ---- stage B tile + per-class sumsq ----
  {
    const int c = tid >> 3;        // class within tile, 0..63
    const int j = tid & 7;         // 8 threads per class
    const int gc = c0 + c;
    const bool valid = gc < C_NUM;
    const f32x4* wrow = reinterpret_cast<const f32x4*>(weight + (size_t)gc * D_EMB);
    float ss = 0.f;
#pragma unroll
    for (int ii = 0; ii < 16; ++ii) {
      const int k4 = ii * 8 + j;   // float4 index within the row, 0..127
      f32x4 v;
      if (valid) v = wrow[k4];
      else       { v[0] = 0.f; v[1] = 0.f; v[2] = 0.f; v[3] = 0.f; }
      ss += v[0]*v[0] + v[1]*v[1] + v[2]*v[2] + v[3]*v[3];
      bf16x4 b;
#pragma unroll
      for (int q = 0; q < 4; ++q) b[q] = f2bf(v[q]);
      int byte = c * 1024 + k4 * 8;          // element k = 4*k4, bf16 -> *2
      byte ^= (c & 7) << 4;                  // XOR swizzle (G4)
      *reinterpret_cast<bf16x4*>(BsB + byte) = b;
    }
    ss += __shfl_xor(ss, 1);
    ss += __shfl_xor(ss, 2);
    ss += __shfl_xor(ss, 4);
    if (j == 0) winv[c] = (valid && ss > 0.f) ? rsqrtf(ss) : 0.f;
  }
  __syncthreads();

  // ---- MFMA K-loop ----
  const int wid = tid >> 6;        // 0..7
  const int lane = tid & 63;
  const int rbase = wid * 64;
  const int lhi = lane >> 4;       // 0..3
  const int llo = lane & 15;

  f32x4 acc[4][4];
#pragma unroll
  for (int mi = 0; mi < 4; ++mi)
#pragma unroll
    for (int ni = 0; ni < 4; ++ni)
#pragma unroll
      for (int q = 0; q < 4; ++q) acc[mi][ni][q] = 0.f;

  for (int k0 = 0; k0 < 512; k0 += 32) {
    const int ka = k0 + lhi * 8;
    bf16x8 a[4], b[4];
#pragma unroll
    for (int mi = 0; mi < 4; ++mi) {
      const int r = rbase + mi * 16 + llo;
      a[mi] = *reinterpret_cast<const bf16x8*>(Aunit + (size_t)r * D_EMB + ka);
    }
#pragma unroll
    for (int ni = 0; ni < 4; ++ni) {
      const int cc = ni * 16 + llo;
      int byte = cc * 1024 + ka * 2;
      byte ^= (cc & 7) << 4;
      b[ni] = *reinterpret_cast<const bf16x8*>(BsB + byte);
    }
#pragma unroll
    for (int mi = 0; mi < 4; ++mi)
#pragma unroll
      for (int ni = 0; ni < 4; ++ni)
        acc[mi][ni] = __builtin_amdgcn_mfma_f32_16x16x32_bf16(a[mi], b[ni], acc[mi][ni], 0, 0, 0);
  }

  // ---- epilogue: margin at label, exp-sum per row ----
  float es[4][4];
#pragma unroll
  for (int mi = 0; mi < 4; ++mi)
#pragma unroll
    for (int q = 0; q < 4; ++q) es[mi][q] = 0.f;

#pragma unroll
  for (int mi = 0; mi < 4; ++mi) {
#pragma unroll
    for (int ni = 0; ni < 4; ++ni) {
      const int ccol = ni * 16 + llo;
      const int gcc = c0 + ccol;
      const float wv = winv[ccol];
      const bool vcol = gcc < C_NUM;
#pragma unroll
      for (int reg = 0; reg < 4; ++reg) {
        const int R = rbase + mi * 16 + lhi * 4 + reg;
        const float cosv = acc[mi][ni][reg] * wv;
        float logit = SCALE_F * cosv;
        if (lab[R] == gcc) {
          float ct = fminf(1.f, fmaxf(-1.f, cosv));
          float lt = SCALE_F * cosf(acosf(ct) + marg[R]);
          logit = lt;
          tlogit[R] = lt;
        }
        es[mi][reg] += vcol ? __expf(logit) : 0.f;
      }
    }
  }

#pragma unroll
  for (int mi = 0; mi < 4; ++mi)
#pragma unroll
    for (int reg = 0; reg < 4; ++reg) {
      float v = es[mi][reg];
      v += __shfl_xor(v, 1);
      v += __shfl_xor(v, 2);
      v += __shfl_xor(v, 4);
      v += __shfl_xor(v, 8);
      if (llo == 0) rowsum[rbase + mi * 16 + lhi * 4 + reg] = v;
    }
  __syncthreads();
  atomicAdd(&sumexp[tid], rowsum[tid]);
}

// ---------------------------------------------------------------------------
// Kernel 4: loss = mean(log(sumexp) - target_logit)
// ---------------------------------------------------------------------------
__global__ __launch_bounds__(512) void k_final(const float* __restrict__ sumexp,
                                               const float* __restrict__ tlogit,
                                               float* __restrict__ out) {
  __shared__ float red[8];
  const int t = threadIdx.x;
  const int lane = t & 63, wid = t >> 6;
  float v = logf(sumexp[t]) - tlogit[t];
#pragma unroll
  for (int m = 1; m < 64; m <<= 1) v += __shfl_xor(v, m);
  if (lane == 0) red[wid] = v;
  __syncthreads();
  if (t == 0) {
    float tot = 0.f;
#pragma unroll
    for (int q = 0; q < 8; ++q) tot += red[q];
    out[0] = tot / 512.f;
  }
}

extern "C" void kernel_launch(void* const* d_in, const int* in_sizes, int n_in,
                              void* d_out, int out_size, void* d_ws, size_t ws_size,
                              hipStream_t stream) {
  const float* emb    = (const float*)d_in[0];
  const int*   labels = (const int*)d_in[1];
  const float* weight = (const float*)d_in[2];
  float* out = (float*)d_out;

  char* ws = (char*)d_ws;
  short* Aunit  = (short*)ws;                       // 512*512*2 = 524288 B
  float* norms  = (float*)(ws + 524288);            // 2 KiB
  float* marg   = (float*)(ws + 524288 + 2048);     // 2 KiB
  float* sumexp = (float*)(ws + 524288 + 4096);     // 2 KiB
  float* tlog   = (float*)(ws + 524288 + 6144);     // 2 KiB

  k_rownorm<<<N_BATCH, 64, 0, stream>>>(emb, Aunit, norms);
  k_stats<<<1, 512, 0, stream>>>(norms, marg, sumexp);
  const int nblk = (C_NUM + 63) / 64;               // 1563
  k_main<<<nblk, 512, 0, stream>>>(Aunit, weight, labels, marg, sumexp, tlog);
  k_final<<<1, 512, 0, stream>>>(sumexp, tlog, out);
}